// Round 1
// baseline (589.064 us; speedup 1.0000x reference)
//
#include <hip/hip_runtime.h>
#include <stdint.h>
#include <math.h>

#pragma clang fp contract(off)

#define NB 4
#define TOTA 261888
#define PRE 2000
#define POST 1000
#define CATN 4768
#define NBL 20

__device__ __forceinline__ unsigned keyF(float f) {
  unsigned u = __float_as_uint(f);
  return (u & 0x80000000u) ? ~u : (u | 0x80000000u);
}

__device__ __forceinline__ int lvlA(int l)   { switch (l) { case 0: return 196608; case 1: return 49152; case 2: return 12288; case 3: return 3072; default: return 768; } }
__device__ __forceinline__ int lvlOff(int l) { switch (l) { case 0: return 0; case 1: return 196608; case 2: return 245760; case 3: return 258048; default: return 261120; } }
__device__ __forceinline__ int lvlK(int l)   { return l == 4 ? 768 : 2000; }
__device__ __forceinline__ int lvlKP(int l)  { return l == 4 ? 768 : 1000; }

struct InPtrs {
  const float *p0, *p1, *p2, *p3, *p4;
  const float *r0, *r1, *r2, *r3, *r4;
  const float *info;
};

// ---------------- Kernel 1: decode + clip + score extract ----------------
__global__ __launch_bounds__(256) void k_decode(InPtrs P, float4* __restrict__ props,
                                                float* __restrict__ scores) {
  int gid = blockIdx.x * 256 + threadIdx.x;
  if (gid >= NB * TOTA) return;
  int b = gid / TOTA, ga = gid % TOTA;
  int Al, off, lg; float st; double S; const float *prp, *rgp;
  if (ga < 196608)      { Al = 196608; off = 0;      lg = 8; st = 4.0f;  S = 256.0;  prp = P.p0; rgp = P.r0; }
  else if (ga < 245760) { Al = 49152;  off = 196608; lg = 7; st = 8.0f;  S = 512.0;  prp = P.p1; rgp = P.r1; }
  else if (ga < 258048) { Al = 12288;  off = 245760; lg = 6; st = 16.0f; S = 1024.0; prp = P.p2; rgp = P.r2; }
  else if (ga < 261120) { Al = 3072;   off = 258048; lg = 5; st = 32.0f; S = 2048.0; prp = P.p3; rgp = P.r3; }
  else                  { Al = 768;    off = 261120; lg = 4; st = 64.0f; S = 4096.0; prp = P.p4; rgp = P.r4; }
  int i = ga - off;
  int cell = i / 3, rr = i - cell * 3;
  int col = cell & ((1 << lg) - 1), row = cell >> lg;
  float cx0 = ((float)col + 0.5f) * st;
  float cy0 = ((float)row + 0.5f) * st;
  const double SQ2 = 1.4142135623730951;
  const double SQH = 0.7071067811865476;
  double swd = (rr == 0) ? SQ2 : (rr == 1 ? 1.0 : SQH);
  double shd = (rr == 0) ? SQH : (rr == 1 ? 1.0 : SQ2);
  float wf = (float)(S * swd), hf = (float)(S * shd);
  float ax1 = cx0 - 0.5f * wf, ay1 = cy0 - 0.5f * hf;
  float ax2 = cx0 + 0.5f * wf, ay2 = cy0 + 0.5f * hf;
  size_t base = (size_t)b * Al + i;
  float sc = prp[base * 2];
  float dx = rgp[base * 4 + 0], dy = rgp[base * 4 + 1];
  float dw = rgp[base * 4 + 2], dh = rgp[base * 4 + 3];
  float wa = ax2 - ax1, ha = ay2 - ay1;
  float cxa = ax1 + 0.5f * wa, cya = ay1 + 0.5f * ha;
  float cx = dx * wa + cxa, cy = dy * ha + cya;
  float w = (float)exp((double)dw) * wa;
  float h = (float)exp((double)dh) * ha;
  float x1 = cx - 0.5f * w, y1 = cy - 0.5f * h;
  float x2 = cx + 0.5f * w, y2 = cy + 0.5f * h;
  float Hc = P.info[b * 3 + 0] - 1.0f, Wc = P.info[b * 3 + 1] - 1.0f;
  float4 o;
  o.x = fminf(fmaxf(x1, 0.0f), Wc);
  o.y = fminf(fmaxf(y1, 0.0f), Hc);
  o.z = fminf(fmaxf(x2, 0.0f), Wc);
  o.w = fminf(fmaxf(y2, 0.0f), Hc);
  props[gid] = o;
  scores[gid] = sc;
}

// ---------------- Kernel 2: per-(b,level) stable top-K ----------------
__device__ void find_bin(unsigned* hist, unsigned* gsum, int nbins, int tid,
                         int* sh_bin, unsigned* sh_rank, unsigned rank) {
  int ng = nbins >> 6;
  if (tid < ng) {
    unsigned s = 0;
    for (int q = 0; q < 64; ++q) s += hist[tid * 64 + q];
    gsum[tid] = s;
  }
  __syncthreads();
  if (tid == 0) {
    unsigned cum = 0; int g;
    for (g = ng - 1; g > 0; --g) { if (cum + gsum[g] >= rank) break; cum += gsum[g]; }
    int bb;
    for (bb = 63; bb > 0; --bb) { unsigned c = hist[g * 64 + bb]; if (cum + c >= rank) break; cum += c; }
    *sh_bin = g * 64 + bb;
    *sh_rank = rank - cum;
  }
  __syncthreads();
}

__global__ __launch_bounds__(1024) void k_topk(const float* __restrict__ scores,
                                               const float4* __restrict__ props,
                                               float4* __restrict__ sBox,
                                               float* __restrict__ sArea,
                                               float* __restrict__ sScore) {
  __shared__ unsigned hist[4096];
  __shared__ unsigned gsum[64];
  __shared__ unsigned long long cand[4096];
  __shared__ int sh_bin;
  __shared__ unsigned sh_rank;
  __shared__ int sh_num;
  int bl = blockIdx.x, b = bl / 5, l = bl % 5;
  int n = lvlA(l), off = lvlOff(l), K = lvlK(l);
  int tid = threadIdx.x;
  const float* sc = scores + (size_t)b * TOTA + off;
  unsigned rank = (unsigned)K;
  // pass 1: bits [31:20]
  for (int q = tid; q < 4096; q += 1024) hist[q] = 0;
  __syncthreads();
  for (int q = tid; q < n; q += 1024) atomicAdd(&hist[keyF(sc[q]) >> 20], 1u);
  __syncthreads();
  find_bin(hist, gsum, 4096, tid, &sh_bin, &sh_rank, rank);
  unsigned b1 = (unsigned)sh_bin; rank = sh_rank;
  __syncthreads();
  // pass 2: bits [19:8]
  for (int q = tid; q < 4096; q += 1024) hist[q] = 0;
  __syncthreads();
  for (int q = tid; q < n; q += 1024) {
    unsigned key = keyF(sc[q]);
    if ((key >> 20) == b1) atomicAdd(&hist[(key >> 8) & 0xFFFu], 1u);
  }
  __syncthreads();
  find_bin(hist, gsum, 4096, tid, &sh_bin, &sh_rank, rank);
  unsigned pre24 = (b1 << 12) | (unsigned)sh_bin; rank = sh_rank;
  __syncthreads();
  // pass 3: bits [7:0]
  for (int q = tid; q < 256; q += 1024) hist[q] = 0;
  __syncthreads();
  for (int q = tid; q < n; q += 1024) {
    unsigned key = keyF(sc[q]);
    if ((key >> 8) == pre24) atomicAdd(&hist[key & 0xFFu], 1u);
  }
  __syncthreads();
  find_bin(hist, gsum, 256, tid, &sh_bin, &sh_rank, rank);
  unsigned Tkey = (pre24 << 8) | (unsigned)sh_bin;
  __syncthreads();
  // compact all keys >= Tkey
  if (tid == 0) sh_num = 0;
  __syncthreads();
  for (int q = tid; q < n; q += 1024) {
    unsigned key = keyF(sc[q]);
    if (key >= Tkey) {
      int pp = atomicAdd(&sh_num, 1);
      if (pp < 4096)
        cand[pp] = ((unsigned long long)key << 32) | (unsigned long long)(0xFFFFFFFFu - (unsigned)q);
    }
  }
  __syncthreads();
  int num = sh_num;
  for (int q = tid; q < 4096; q += 1024) if (q >= num) cand[q] = 0ull;
  __syncthreads();
  // bitonic sort 4096 descending
  for (int kk = 2; kk <= 4096; kk <<= 1)
    for (int jj = kk >> 1; jj > 0; jj >>= 1) {
      for (int idx = tid; idx < 4096; idx += 1024) {
        int p2 = idx ^ jj;
        if (p2 > idx) {
          unsigned long long x = cand[idx], y = cand[p2];
          bool up = (idx & kk) == 0;
          if (up ? (x < y) : (x > y)) { cand[idx] = y; cand[p2] = x; }
        }
      }
      __syncthreads();
    }
  // emit sorted top-K: boxes, areas, scores
  for (int j = tid; j < K; j += 1024) {
    unsigned long long e = cand[j];
    unsigned idx = 0xFFFFFFFFu - (unsigned)(e & 0xFFFFFFFFull);
    float4 bx = props[(size_t)b * TOTA + off + idx];
    float area = fmaxf(bx.z - bx.x, 0.0f) * fmaxf(bx.w - bx.y, 0.0f);
    sBox[bl * PRE + j] = bx;
    sArea[bl * PRE + j] = area;
    sScore[bl * PRE + j] = sc[idx];
  }
}

// ---------------- Kernel 3: IoU suppression bitmask ----------------
__global__ __launch_bounds__(256) void k_mask(const float4* __restrict__ sBox,
                                              const float* __restrict__ sArea,
                                              unsigned long long* __restrict__ mask) {
  int bi = blockIdx.x;
  int bl = bi >> 8, rem = bi & 255, ic = rem >> 3, wc = rem & 7;
  int l = bl % 5, K = lvlK(l);
  if (ic * 64 >= K) return;
  __shared__ float4 jb[256];
  __shared__ float ja[256];
  int tid = threadIdx.x;
  int j0 = wc * 256;
  {
    int j = j0 + tid;
    if (j < K) { jb[tid] = sBox[bl * PRE + j]; ja[tid] = sArea[bl * PRE + j]; }
    else { jb[tid] = make_float4(0.0f, 0.0f, 0.0f, 0.0f); ja[tid] = 0.0f; }
  }
  __syncthreads();
  int iL = tid >> 2, wL = tid & 3;
  int i = ic * 64 + iL;
  if (i >= K) return;
  float4 a4 = sBox[bl * PRE + i];
  float ai = sArea[bl * PRE + i];
  unsigned long long bits = 0;
  int tb = wL * 64;
  for (int t = 0; t < 64; ++t) {
    int j = j0 + tb + t;
    if (j < K && j > i) {
      float4 b4 = jb[tb + t];
      float ltx = fmaxf(a4.x, b4.x), lty = fmaxf(a4.y, b4.y);
      float rbx = fminf(a4.z, b4.z), rby = fminf(a4.w, b4.w);
      float wx = fmaxf(rbx - ltx, 0.0f), wy = fmaxf(rby - lty, 0.0f);
      float inter = wx * wy;
      float den = fmaxf(ai + ja[tb + t] - inter, 1e-9f);
      float iou = inter / den;
      if (iou > 0.7f) bits |= (1ull << t);
    }
  }
  mask[((size_t)bl * PRE + i) * 32 + (wc * 4 + wL)] = bits;
}

// ---------------- Kernel 4: serial NMS scan + stable pack ----------------
__global__ __launch_bounds__(64) void k_scan(const unsigned long long* __restrict__ mask,
                                             const float4* __restrict__ sBox,
                                             const float* __restrict__ sScore,
                                             float* __restrict__ catScore,
                                             float4* __restrict__ catBox) {
  int bl = blockIdx.x, b = bl / 5, l = bl % 5;
  int K = lvlK(l), KP = lvlKP(l), co = l * 1000;
  int lane = threadIdx.x;
  const unsigned long long* mrow = mask + (size_t)bl * PRE * 32;
  bool lv = lane < 32;
  unsigned long long remv = 0;
  unsigned long long buf[16];
#pragma unroll
  for (int d = 0; d < 16; ++d) buf[d] = (lv && d < K) ? mrow[(size_t)d * 32 + lane] : 0ull;
  for (int i0 = 0; i0 < K; i0 += 16) {
#pragma unroll
    for (int d = 0; d < 16; ++d) {
      int ii = i0 + d;
      unsigned long long row = buf[d];
      int nx = ii + 16;
      buf[d] = (lv && nx < K) ? mrow[(size_t)nx * 32 + lane] : 0ull;
      unsigned lo = (unsigned)remv, hi = (unsigned)(remv >> 32);
      unsigned sel = ((ii >> 5) & 1) ? hi : lo;
      unsigned w32 = __builtin_amdgcn_readlane(sel, ii >> 6);
      if (!((w32 >> (ii & 31)) & 1u)) remv |= row;
    }
  }
  unsigned long long valid = 0ull;
  if (lv) {
    int rem = K - lane * 64;
    valid = (rem >= 64) ? ~0ull : (rem <= 0 ? 0ull : ((1ull << rem) - 1ull));
  }
  unsigned long long keepw = (~remv) & valid;
  unsigned long long suppw = remv & valid;
  __shared__ int list[1000];
  unsigned long long lmask = (1ull << lane) - 1ull;
  int base = 0;
  for (int w2 = 0; w2 < 32 && base < KP; ++w2) {
    unsigned long long word = __shfl(keepw, w2);
    int pre = __popcll(word & lmask);
    if (((word >> lane) & 1ull) && (base + pre) < KP) list[base + pre] = w2 * 64 + lane;
    base += __popcll(word);
  }
  int totalKept = base;
  if (totalKept < KP) {
    int b2 = totalKept;
    for (int w2 = 0; w2 < 32 && b2 < KP; ++w2) {
      unsigned long long word = __shfl(suppw, w2);
      int pre = __popcll(word & lmask);
      if (((word >> lane) & 1ull) && (b2 + pre) < KP) list[b2 + pre] = w2 * 64 + lane;
      b2 += __popcll(word);
    }
  }
  __syncthreads();
  for (int t = lane; t < KP; t += 64) {
    int j = list[t];
    float s = (t < totalKept) ? sScore[bl * PRE + j] : -1.0f;
    catScore[b * CATN + co + t] = s;
    catBox[b * CATN + co + t] = sBox[bl * PRE + j];
  }
}

// ---------------- Kernel 5: final per-image top-1000 + emit ----------------
__global__ __launch_bounds__(1024) void k_final(const float* __restrict__ catScore,
                                                const float4* __restrict__ catBox,
                                                float* __restrict__ out) {
  __shared__ unsigned long long arr[8192];
  int b = blockIdx.x, tid = threadIdx.x;
  for (int q = tid; q < 8192; q += 1024) {
    unsigned long long e = 0ull;
    if (q < CATN)
      e = ((unsigned long long)keyF(catScore[b * CATN + q]) << 32) |
          (unsigned long long)(0xFFFFFFFFu - (unsigned)q);
    arr[q] = e;
  }
  __syncthreads();
  for (int kk = 2; kk <= 8192; kk <<= 1)
    for (int jj = kk >> 1; jj > 0; jj >>= 1) {
      for (int idx = tid; idx < 8192; idx += 1024) {
        int p2 = idx ^ jj;
        if (p2 > idx) {
          unsigned long long x = arr[idx], y = arr[p2];
          bool up = (idx & kk) == 0;
          if (up ? (x < y) : (x > y)) { arr[idx] = y; arr[p2] = x; }
        }
      }
      __syncthreads();
    }
  for (int t = tid; t < POST; t += 1024) {
    unsigned long long e = arr[t];
    unsigned kh = (unsigned)(e >> 32);
    float4 bx = make_float4(0.0f, 0.0f, 0.0f, 0.0f);
    if (kh >= 0x80000000u) {  // score >= 0
      unsigned p = 0xFFFFFFFFu - (unsigned)(e & 0xFFFFFFFFull);
      bx = catBox[b * CATN + p];
    }
    float* o = out + ((size_t)b * POST + t) * 5;
    o[0] = (float)b; o[1] = bx.x; o[2] = bx.y; o[3] = bx.z; o[4] = bx.w;
  }
}

extern "C" void kernel_launch(void* const* d_in, const int* in_sizes, int n_in,
                              void* d_out, int out_size, void* d_ws, size_t ws_size,
                              hipStream_t stream) {
  const int prSz[5] = {1572864, 393216, 98304, 24576, 6144};
  const int rgSz[5] = {3145728, 786432, 196608, 49152, 12288};
  const float* pr[5] = {nullptr, nullptr, nullptr, nullptr, nullptr};
  const float* rg[5] = {nullptr, nullptr, nullptr, nullptr, nullptr};
  const float* info = nullptr;
  for (int i = 0; i < n_in; ++i) {
    int s = in_sizes[i];
    bool m = false;
    for (int l = 0; l < 5; ++l) {
      if (s == prSz[l]) { pr[l] = (const float*)d_in[i]; m = true; break; }
      if (s == rgSz[l]) { rg[l] = (const float*)d_in[i]; m = true; break; }
    }
    if (!m && s == 12) info = (const float*)d_in[i];
  }
  InPtrs P;
  P.p0 = pr[0]; P.p1 = pr[1]; P.p2 = pr[2]; P.p3 = pr[3]; P.p4 = pr[4];
  P.r0 = rg[0]; P.r1 = rg[1]; P.r2 = rg[2]; P.r3 = rg[3]; P.r4 = rg[4];
  P.info = info;

  char* w = (char*)d_ws;
  float4* props = (float4*)w;                         w += (size_t)NB * TOTA * 16;
  float4* sBox = (float4*)w;                          w += (size_t)NBL * PRE * 16;
  float4* catBox = (float4*)w;                        w += (size_t)NB * CATN * 16;
  unsigned long long* mask = (unsigned long long*)w;  w += (size_t)NBL * PRE * 32 * 8;
  float* scores = (float*)w;                          w += (size_t)NB * TOTA * 4;
  float* sArea = (float*)w;                           w += (size_t)NBL * PRE * 4;
  float* sScore = (float*)w;                          w += (size_t)NBL * PRE * 4;
  float* catScore = (float*)w;                        w += (size_t)NB * CATN * 4;
  (void)ws_size; (void)out_size;

  k_decode<<<(NB * TOTA + 255) / 256, 256, 0, stream>>>(P, props, scores);
  k_topk<<<NBL, 1024, 0, stream>>>(scores, props, sBox, sArea, sScore);
  k_mask<<<NBL * 256, 256, 0, stream>>>(sBox, sArea, mask);
  k_scan<<<NBL, 64, 0, stream>>>(mask, sBox, sScore, catScore, catBox);
  k_final<<<NB, 1024, 0, stream>>>(catScore, catBox, (float*)d_out);
}